// Round 7
// baseline (296.260 us; speedup 1.0000x reference)
//
#include <hip/hip_runtime.h>
#include <hip/hip_bf16.h>
#include <math.h>

#define LP 1000
#define NCMP 64
#define NSPLIT 4

typedef _Float16 f16;
typedef f16   v8h __attribute__((ext_vector_type(8)));
typedef float v4f __attribute__((ext_vector_type(4)));

__device__ __forceinline__ float rcp_fast(float x) { return __builtin_amdgcn_rcpf(x); }
__device__ __forceinline__ void fsplit(float x, f16& h, f16& l) {
    h = (f16)x; l = (f16)(x - (float)h);
}
// fp32x8 -> fp16 hi/lo vectors, in registers (bit-identical to materialized split)
__device__ __forceinline__ void fs8(const float4& f0, const float4& f1, v8h& h, v8h& l) {
    const float x[8] = {f0.x, f0.y, f0.z, f0.w, f1.x, f1.y, f1.z, f1.w};
    #pragma unroll
    for (int i = 0; i < 8; ++i) {
        f16 hh = (f16)x[i];
        h[i] = hh;
        l[i] = (f16)(x[i] - (float)hh);
    }
}

struct H4 { f16 a, b, c, d; };   // 8-byte fp16 quad

// ---------------- GEMM core: Y[M,128] = op(X)[M,K] @ W[K,128] + b ----------------
// 32-row tile, 256 threads, thread 4x4, X transposed in LDS, software-pipelined.
__device__ __forceinline__ void gemm_core(float (*Ws)[128], float (*Xt)[36],
                                          const float* X, const float* W, const float* bias,
                                          float* Y, int K, int rowbase, bool relu_in)
{
    const int t  = threadIdx.x;
    const int r0 = (t >> 5) * 4;
    const int c0 = (t & 31) * 4;
    const int xr = t >> 3, xk = (t & 7) << 2;
    const int xrow = rowbase + xr;
    float4 xv = *(const float4*)(X + (long)xrow * K + xk);
    float4 wv[4];
    #pragma unroll
    for (int u = 0; u < 4; ++u) {
        int s = t + u * 256, r = s >> 5, cb = (s & 31) << 2;
        wv[u] = *(const float4*)(W + (long)r * 128 + cb);
    }
    float acc[4][4] = {};
    for (int k0 = 0; k0 < K; k0 += 32) {
        float4 xs = xv;
        if (relu_in) { xs.x = fmaxf(xs.x,0.f); xs.y = fmaxf(xs.y,0.f);
                       xs.z = fmaxf(xs.z,0.f); xs.w = fmaxf(xs.w,0.f); }
        Xt[xk+0][xr] = xs.x; Xt[xk+1][xr] = xs.y; Xt[xk+2][xr] = xs.z; Xt[xk+3][xr] = xs.w;
        #pragma unroll
        for (int u = 0; u < 4; ++u) {
            int s = t + u * 256, r = s >> 5, cb = (s & 31) << 2;
            *(float4*)&Ws[r][cb] = wv[u];
        }
        __syncthreads();
        if (k0 + 32 < K) {
            xv = *(const float4*)(X + (long)xrow * K + k0 + 32 + xk);
            #pragma unroll
            for (int u = 0; u < 4; ++u) {
                int s = t + u * 256, r = s >> 5, cb = (s & 31) << 2;
                wv[u] = *(const float4*)(W + (long)(k0 + 32 + r) * 128 + cb);
            }
        }
        #pragma unroll
        for (int kk = 0; kk < 32; ++kk) {
            float4 w4 = *(const float4*)&Ws[kk][c0];
            float4 x4 = *(const float4*)&Xt[kk][r0];
            acc[0][0] = fmaf(x4.x, w4.x, acc[0][0]); acc[0][1] = fmaf(x4.x, w4.y, acc[0][1]);
            acc[0][2] = fmaf(x4.x, w4.z, acc[0][2]); acc[0][3] = fmaf(x4.x, w4.w, acc[0][3]);
            acc[1][0] = fmaf(x4.y, w4.x, acc[1][0]); acc[1][1] = fmaf(x4.y, w4.y, acc[1][1]);
            acc[1][2] = fmaf(x4.y, w4.z, acc[1][2]); acc[1][3] = fmaf(x4.y, w4.w, acc[1][3]);
            acc[2][0] = fmaf(x4.z, w4.x, acc[2][0]); acc[2][1] = fmaf(x4.z, w4.y, acc[2][1]);
            acc[2][2] = fmaf(x4.z, w4.z, acc[2][2]); acc[2][3] = fmaf(x4.z, w4.w, acc[2][3]);
            acc[3][0] = fmaf(x4.w, w4.x, acc[3][0]); acc[3][1] = fmaf(x4.w, w4.y, acc[3][1]);
            acc[3][2] = fmaf(x4.w, w4.z, acc[3][2]); acc[3][3] = fmaf(x4.w, w4.w, acc[3][3]);
        }
        __syncthreads();
    }
    float4 bv = bias ? *(const float4*)(bias + c0) : make_float4(0.f,0.f,0.f,0.f);
    #pragma unroll
    for (int i = 0; i < 4; ++i) {
        int row = rowbase + r0 + i;
        float4 o;
        o.x = acc[i][0] + bv.x; o.y = acc[i][1] + bv.y;
        o.z = acc[i][2] + bv.z; o.w = acc[i][3] + bv.w;
        *(float4*)(Y + (long)row * 128 + c0) = o;
    }
}

// Same GEMM but epilogue writes the TRANSPOSED fp16 hi/lo split: T[n][k] for Y[k][n].
__device__ __forceinline__ void gemm_coreT(float (*Ws)[128], float (*Xt)[36],
                                           const float* X, const float* W,
                                           f16* ThT, f16* TlT, int KT, int rowbase)
{
    const int t  = threadIdx.x;
    const int r0 = (t >> 5) * 4;
    const int c0 = (t & 31) * 4;
    const int xr = t >> 3, xk = (t & 7) << 2;
    const int xrow = rowbase + xr;
    float4 xv = *(const float4*)(X + (long)xrow * 128 + xk);
    float4 wv[4];
    #pragma unroll
    for (int u = 0; u < 4; ++u) {
        int s = t + u * 256, r = s >> 5, cb = (s & 31) << 2;
        wv[u] = *(const float4*)(W + (long)r * 128 + cb);
    }
    float acc[4][4] = {};
    for (int k0 = 0; k0 < 128; k0 += 32) {
        Xt[xk+0][xr] = xv.x; Xt[xk+1][xr] = xv.y; Xt[xk+2][xr] = xv.z; Xt[xk+3][xr] = xv.w;
        #pragma unroll
        for (int u = 0; u < 4; ++u) {
            int s = t + u * 256, r = s >> 5, cb = (s & 31) << 2;
            *(float4*)&Ws[r][cb] = wv[u];
        }
        __syncthreads();
        if (k0 + 32 < 128) {
            xv = *(const float4*)(X + (long)xrow * 128 + k0 + 32 + xk);
            #pragma unroll
            for (int u = 0; u < 4; ++u) {
                int s = t + u * 256, r = s >> 5, cb = (s & 31) << 2;
                wv[u] = *(const float4*)(W + (long)(k0 + 32 + r) * 128 + cb);
            }
        }
        #pragma unroll
        for (int kk = 0; kk < 32; ++kk) {
            float4 w4 = *(const float4*)&Ws[kk][c0];
            float4 x4 = *(const float4*)&Xt[kk][r0];
            acc[0][0] = fmaf(x4.x, w4.x, acc[0][0]); acc[0][1] = fmaf(x4.x, w4.y, acc[0][1]);
            acc[0][2] = fmaf(x4.x, w4.z, acc[0][2]); acc[0][3] = fmaf(x4.x, w4.w, acc[0][3]);
            acc[1][0] = fmaf(x4.y, w4.x, acc[1][0]); acc[1][1] = fmaf(x4.y, w4.y, acc[1][1]);
            acc[1][2] = fmaf(x4.y, w4.z, acc[1][2]); acc[1][3] = fmaf(x4.y, w4.w, acc[1][3]);
            acc[2][0] = fmaf(x4.z, w4.x, acc[2][0]); acc[2][1] = fmaf(x4.z, w4.y, acc[2][1]);
            acc[2][2] = fmaf(x4.z, w4.z, acc[2][2]); acc[2][3] = fmaf(x4.z, w4.w, acc[2][3]);
            acc[3][0] = fmaf(x4.w, w4.x, acc[3][0]); acc[3][1] = fmaf(x4.w, w4.y, acc[3][1]);
            acc[3][2] = fmaf(x4.w, w4.z, acc[3][2]); acc[3][3] = fmaf(x4.w, w4.w, acc[3][3]);
        }
        __syncthreads();
    }
    // transposed split epilogue: T[col][rowK], rowK in [0,KT)
    #pragma unroll
    for (int i = 0; i < 4; ++i) {
        int row = rowbase + r0 + i;
        #pragma unroll
        for (int j = 0; j < 4; ++j) {
            f16 h, l; fsplit(acc[i][j], h, l);
            long o = (long)(c0 + j) * KT + row;
            ThT[o] = h; TlT[o] = l;
        }
    }
}

// ---- pre0b: 0-9: Wp=emb_w@wq_w -> WpT hi/lo (transposed split, no fp32 Wp);
//      10: bp + zero Asum/cpe; 11-14: Wvo=wv_w@wo_w; 15: bvo; 16-23: wk_w -> WkT hi/lo ----
__global__ __launch_bounds__(256) void pre0_k(const float* __restrict__ emb_w, const float* __restrict__ emb_b,
                                              const float* __restrict__ wq_w, const float* __restrict__ wq_b,
                                              const float* __restrict__ wk_w,
                                              const float* __restrict__ wv_w, const float* __restrict__ wv_b,
                                              const float* __restrict__ wo_w, const float* __restrict__ wo_b,
                                              f16* __restrict__ WpThi, f16* __restrict__ WpTlo,
                                              f16* __restrict__ WkThi, f16* __restrict__ WkTlo,
                                              float* __restrict__ bp,
                                              float* __restrict__ Wvo, float* __restrict__ bvo,
                                              float* __restrict__ zbase)
{
    __shared__ __align__(16) float Ws[32][128];
    __shared__ __align__(16) float Xt[32][36];
    const int bid = blockIdx.x;
    const int t = threadIdx.x;
    if (bid < 10) { gemm_coreT(Ws, Xt, emb_w, wq_w, WpThi, WpTlo, 320, bid * 32); return; }
    if (bid >= 11 && bid < 15) { gemm_core(Ws, Xt, wv_w, wo_w, nullptr, Wvo, 128, (bid - 11) * 32, false); return; }
    if (bid >= 16) {
        // wk_w [128][128] -> WkT hi/lo [n][k]; 8 blocks x 2048 elems
        #pragma unroll
        for (int u = 0; u < 8; ++u) {
            int idx = (bid - 16) * 2048 + u * 256 + t;
            int k = idx >> 7, n = idx & 127;
            f16 h, l; fsplit(wk_w[idx], h, l);
            WkThi[(long)n * 128 + k] = h; WkTlo[(long)n * 128 + k] = l;
        }
        return;
    }
    if (bid == 10 && t >= 128) {
        for (int i = t - 128; i < 1032; i += 128) zbase[i] = 0.f;
        return;
    }
    if (t < 128) {
        const float* vb = (bid == 10) ? emb_b : wv_b;
        const float* Wm = (bid == 10) ? wq_w  : wo_w;
        const float* ab = (bid == 10) ? wq_b  : wo_b;
        float a0 = 0.f, a1 = 0.f, a2 = 0.f, a3 = 0.f;
        for (int k = 0; k < 128; k += 4) {
            a0 = fmaf(vb[k+0], Wm[(k+0)*128 + t], a0);
            a1 = fmaf(vb[k+1], Wm[(k+1)*128 + t], a1);
            a2 = fmaf(vb[k+2], Wm[(k+2)*128 + t], a2);
            a3 = fmaf(vb[k+3], Wm[(k+3)*128 + t], a3);
        }
        float* dst = (bid == 10) ? bp : bvo;
        dst[t] = (a0 + a1) + (a2 + a3) + ab[t];
    }
}

// ---- qkv3b: split-fp16 MFMA GEMM for Q (K=320) and K (K=128) + Cj + V^T split. ----
// 0-127: Q tiles; 128-255: K tiles; 256-271: Cj (scalar gemm_core); 272-521: V^T hi/lo split.
__global__ __launch_bounds__(256) void qkv3_k(
    const float* __restrict__ PE, const float* __restrict__ PFX,
    const f16* __restrict__ WpThi, const f16* __restrict__ WpTlo,
    const f16* __restrict__ WkThi, const f16* __restrict__ WkTlo,
    const float* __restrict__ bp, const float* __restrict__ wk_b,
    const float* __restrict__ CF, const float* __restrict__ jc_w, const float* __restrict__ jc_b,
    f16* __restrict__ Qhi, f16* __restrict__ Qlo,
    f16* __restrict__ Khi, f16* __restrict__ Klo,
    f16* __restrict__ Vthi, f16* __restrict__ Vtlo,
    float* __restrict__ Cj)
{
    __shared__ __align__(16) float Ws[32][128];
    __shared__ __align__(16) float Xt[32][36];
    const int bid = blockIdx.x;
    const int t = threadIdx.x;
    if (bid >= 272) {
        // V^T split (V = raw PFX), [b][d][1024] fp16 hi/lo
        const int rb = (bid - 272) * 32;
        const int d = t >> 1, half = t & 1;
        #pragma unroll 4
        for (int i = 0; i < 16; ++i) {
            int row = rb + half * 16 + i;
            int bb = row / 1000, rr = row - bb * 1000;
            float v = PFX[(long)row * 128 + d];
            f16 h, l; fsplit(v, h, l);
            long o = ((long)bb * 128 + d) * 1024 + rr;
            Vthi[o] = h; Vtlo[o] = l;
        }
        return;
    }
    if (bid >= 256) { gemm_core(Ws, Xt, CF, jc_w, jc_b, Cj, 128, (bid - 256) * 32, true); return; }
    const bool isQ = bid < 128;
    const int b = (bid & 127) >> 4, tile = bid & 15;
    const int KD  = isQ ? 320 : 128;
    const int NCH = isQ ? 10 : 4;
    const float* A = isQ ? PE : PFX;
    const f16* Bhi = isQ ? WpThi : WkThi;
    const f16* Blo = isQ ? WpTlo : WkTlo;
    const float* bias = isQ ? bp : wk_b;
    f16* Yhi = isQ ? Qhi : Khi;
    f16* Ylo = isQ ? Qlo : Klo;

    const int wv = t >> 6, lane = t & 63, quad = lane >> 4, l4 = lane & 15;
    int arow = tile * 64 + wv * 16 + l4; if (arow >= LP) arow = LP - 1;
    const float* a_p = A + ((long)b * LP + arow) * KD;

    v4f acc[8];
    #pragma unroll
    for (int dt = 0; dt < 8; ++dt) acc[dt] = (v4f){0.f, 0.f, 0.f, 0.f};

    for (int kt = 0; kt < NCH; ++kt) {
        const int ko = kt * 32 + quad * 8;
        float4 f0 = *(const float4*)(a_p + ko);
        float4 f1 = *(const float4*)(a_p + ko + 4);
        v8h ah, al;
        fs8(f0, f1, ah, al);
        #pragma unroll
        for (int dt = 0; dt < 8; ++dt) {
            const long bo = (long)(dt * 16 + l4) * KD + ko;
            v8h bh = *(const v8h*)(Bhi + bo);
            v8h bl = *(const v8h*)(Blo + bo);
            acc[dt] = __builtin_amdgcn_mfma_f32_16x16x32_f16(ah, bh, acc[dt], 0, 0, 0);
            acc[dt] = __builtin_amdgcn_mfma_f32_16x16x32_f16(ah, bl, acc[dt], 0, 0, 0);
            acc[dt] = __builtin_amdgcn_mfma_f32_16x16x32_f16(al, bh, acc[dt], 0, 0, 0);
        }
    }
    // epilogue: C-layout (row = tile*64 + wv*16 + quad*4 + r, col = dt*16 + l4)
    #pragma unroll
    for (int dt = 0; dt < 8; ++dt) {
        const int col = dt * 16 + l4;
        const float bv = bias[col];
        #pragma unroll
        for (int r = 0; r < 4; ++r) {
            int row = tile * 64 + wv * 16 + quad * 4 + r;
            long o = ((long)b * 1024 + row) * 128 + col;
            f16 h, l; fsplit(acc[dt][r] + bv, h, l);
            Yhi[o] = h; Ylo[o] = l;
        }
    }
}

// ---------------- flash7: split-fp16 MFMA flash. TQ=64 (4 waves x 16-row band), TK=64 ----------
__global__ __launch_bounds__(256) void flash7_k(const f16* __restrict__ Qhi, const f16* __restrict__ Qlo,
                                                const f16* __restrict__ Khi, const f16* __restrict__ Klo,
                                                const f16* __restrict__ Vthi, const f16* __restrict__ Vtlo,
                                                float* __restrict__ Opart,
                                                float* __restrict__ mpart, float* __restrict__ lpart)
{
    __shared__ __align__(16) f16 KVhi[9216];     // K: [64][136] (<=8704) ; V^T: [128][72] (9216)
    __shared__ __align__(16) f16 KVlo[9216];
    __shared__ __align__(16) f16 Pshi[4][16 * 72];
    __shared__ __align__(16) f16 Pslo[4][16 * 72];
    const int t    = threadIdx.x;
    const int wv   = t >> 6;
    const int lane = t & 63;
    const int quad = lane >> 4;
    const int l4   = lane & 15;
    const int qt = blockIdx.x, sp = blockIdx.y, b = blockIdx.z;
    const int q0 = qt * 64;
    const float SCALE = 0.08838834764831845f;    // 1/sqrt(128)
    const float L2E   = 1.4426950408889634f;

    int qrow = q0 + wv * 16 + l4; if (qrow >= LP) qrow = LP - 1;
    const long qbase = ((long)b * 1024 + qrow) * 128;
    v8h qh[4], ql[4];
    #pragma unroll
    for (int kt4 = 0; kt4 < 4; ++kt4) {
        qh[kt4] = *(const v8h*)(Qhi + qbase + kt4 * 32 + quad * 8);
        ql[kt4] = *(const v8h*)(Qlo + qbase + kt4 * 32 + quad * 8);
    }
    float m_i[4] = { -3.0e38f, -3.0e38f, -3.0e38f, -3.0e38f };
    float l_i[4] = { 0.f, 0.f, 0.f, 0.f };
    v4f  O[8];
    #pragma unroll
    for (int dt = 0; dt < 8; ++dt) O[dt] = (v4f){0.f, 0.f, 0.f, 0.f};

    for (int kt = sp * 4; kt < sp * 4 + 4; ++kt) {
        const int key0 = kt * 64;
        __syncthreads();                              // (A) prev PV done with KV buffers
        #pragma unroll
        for (int u = 0; u < 4; ++u) {                 // stage K hi/lo (64x128 fp16 each)
            int ch = t + u * 256;
            int r = ch >> 4, co = (ch & 15) * 8;
            long ga = ((long)b * 1024 + key0 + r) * 128 + co;
            *(v8h*)(KVhi + r * 136 + co) = *(const v8h*)(Khi + ga);
            *(v8h*)(KVlo + r * 136 + co) = *(const v8h*)(Klo + ga);
        }
        __syncthreads();                              // (B) K visible
        v8h vh[4], vl[4];
        #pragma unroll
        for (int u = 0; u < 4; ++u) {                 // V^T prefetch (in flight under QK)
            int ch = t + u * 256;
            int d = ch >> 3, co = (ch & 7) * 8;
            long ga = ((long)b * 128 + d) * 1024 + key0 + co;
            vh[u] = *(const v8h*)(Vthi + ga);
            vl[u] = *(const v8h*)(Vtlo + ga);
        }
        // ---- QK^T ----
        v4f S[4];
        #pragma unroll
        for (int nt = 0; nt < 4; ++nt) S[nt] = (v4f){0.f, 0.f, 0.f, 0.f};
        #pragma unroll
        for (int nt = 0; nt < 4; ++nt) {
            const int rb = (nt * 16 + l4) * 136;
            #pragma unroll
            for (int kt4 = 0; kt4 < 4; ++kt4) {
                v8h bh = *(const v8h*)(KVhi + rb + kt4 * 32 + quad * 8);
                v8h bl = *(const v8h*)(KVlo + rb + kt4 * 32 + quad * 8);
                S[nt] = __builtin_amdgcn_mfma_f32_16x16x32_f16(qh[kt4], bh, S[nt], 0, 0, 0);
                S[nt] = __builtin_amdgcn_mfma_f32_16x16x32_f16(qh[kt4], bl, S[nt], 0, 0, 0);
                S[nt] = __builtin_amdgcn_mfma_f32_16x16x32_f16(ql[kt4], bh, S[nt], 0, 0, 0);
            }
        }
        #pragma unroll
        for (int nt = 0; nt < 4; ++nt) {
            bool valid = (key0 + nt * 16 + l4) < LP;
            #pragma unroll
            for (int r = 0; r < 4; ++r)
                S[nt][r] = valid ? S[nt][r] * SCALE : -3.0e38f;
        }
        float alpha[4];
        #pragma unroll
        for (int r = 0; r < 4; ++r) {
            float tm = fmaxf(fmaxf(S[0][r], S[1][r]), fmaxf(S[2][r], S[3][r]));
            tm = fmaxf(tm, __shfl_xor(tm, 1));
            tm = fmaxf(tm, __shfl_xor(tm, 2));
            tm = fmaxf(tm, __shfl_xor(tm, 4));
            tm = fmaxf(tm, __shfl_xor(tm, 8));
            float mnew = fmaxf(m_i[r], tm);
            alpha[r] = exp2f((m_i[r] - mnew) * L2E);
            float ps = 0.f;
            #pragma unroll
            for (int nt = 0; nt < 4; ++nt) {
                float p = exp2f((S[nt][r] - mnew) * L2E);
                S[nt][r] = p;
                ps += p;
            }
            ps += __shfl_xor(ps, 1);
            ps += __shfl_xor(ps, 2);
            ps += __shfl_xor(ps, 4);
            ps += __shfl_xor(ps, 8);
            l_i[r] = l_i[r] * alpha[r] + ps;
            m_i[r] = mnew;
        }
        #pragma unroll
        for (int dt = 0; dt < 8; ++dt) {
            O[dt][0] *= alpha[0]; O[dt][1] *= alpha[1];
            O[dt][2] *= alpha[2]; O[dt][3] *= alpha[3];
        }
        __syncthreads();                              // (C) QK reads of KV done
        #pragma unroll
        for (int u = 0; u < 4; ++u) {                 // V regs -> LDS (overwrite K)
            int ch = t + u * 256;
            int d = ch >> 3, co = (ch & 7) * 8;
            *(v8h*)(KVhi + d * 72 + co) = vh[u];
            *(v8h*)(KVlo + d * 72 + co) = vl[u];
        }
        #pragma unroll
        for (int nt = 0; nt < 4; ++nt) {
            int col = nt * 16 + l4;
            #pragma unroll
            for (int r = 0; r < 4; ++r) {
                f16 ph, pl; fsplit(S[nt][r], ph, pl);
                Pshi[wv][(quad * 4 + r) * 72 + col] = ph;
                Pslo[wv][(quad * 4 + r) * 72 + col] = pl;
            }
        }
        __syncthreads();                              // (D) V visible
        // ---- PV ----
        #pragma unroll
        for (int kc = 0; kc < 2; ++kc) {
            v8h pah = *(const v8h*)(Pshi[wv] + l4 * 72 + kc * 32 + quad * 8);
            v8h pal = *(const v8h*)(Pslo[wv] + l4 * 72 + kc * 32 + quad * 8);
            #pragma unroll
            for (int dt = 0; dt < 8; ++dt) {
                v8h vfh = *(const v8h*)(KVhi + (dt * 16 + l4) * 72 + kc * 32 + quad * 8);
                v8h vfl = *(const v8h*)(KVlo + (dt * 16 + l4) * 72 + kc * 32 + quad * 8);
                O[dt] = __builtin_amdgcn_mfma_f32_16x16x32_f16(pah, vfh, O[dt], 0, 0, 0);
                O[dt] = __builtin_amdgcn_mfma_f32_16x16x32_f16(pah, vfl, O[dt], 0, 0, 0);
                O[dt] = __builtin_amdgcn_mfma_f32_16x16x32_f16(pal, vfh, O[dt], 0, 0, 0);
            }
        }
    }
    #pragma unroll
    for (int r = 0; r < 4; ++r) {
        int row = q0 + wv * 16 + quad * 4 + r;
        if (row < LP) {
            long base = (long)sp * 1024000 + ((long)b * LP + row) * 128;
            #pragma unroll
            for (int dt = 0; dt < 8; ++dt)
                Opart[base + dt * 16 + l4] = O[dt][r];
            if (l4 == 0) {
                mpart[(long)sp * 8000 + b * LP + row] = m_i[r];
                lpart[(long)sp * 8000 + b * LP + row] = l_i[r];
            }
        }
    }
}

// ---------------- mt1ab: NSPLIT merge + wo GEMM + jp GEMM, fused, 3 barriers total ----------
__global__ __launch_bounds__(256) void mt1ab_k(
    const float* __restrict__ Opart, const float* __restrict__ mp, const float* __restrict__ lp,
    const float* __restrict__ Wvo, const float* __restrict__ bvo,
    const float* __restrict__ jp_w, const float* __restrict__ jp_b,
    float* __restrict__ PF, float* __restrict__ PJ)
{
    __shared__ __align__(16) float Ws[128][128];   // 64 KB
    __shared__ __align__(16) float Xs[16][132];
    const int t  = threadIdx.x;
    const int p0 = blockIdx.x * 16;
    const int b  = blockIdx.y;
    const float L2E = 1.4426950408889634f;
    const int r0 = (t >> 5) * 2;
    const int c0 = (t & 31) * 4;

    #pragma unroll
    for (int u = 0; u < 16; ++u) {
        int s = t + u * 256, r = s >> 5, cb = (s & 31) << 2;
        *(float4*)&Ws[r][cb] = *(const float4*)(Wvo + (long)r * 128 + cb);
    }
    {
        const int pr = t >> 4, pc = (t & 15) << 3;
        int grow = p0 + pr; if (grow > LP - 1) grow = LP - 1;
        const long g = (long)b * LP + grow;
        float mm = -3.0e38f;
        #pragma unroll
        for (int s = 0; s < NSPLIT; ++s) mm = fmaxf(mm, mp[g + (long)s * 8000]);
        float wgt[NSPLIT]; float ls = 0.f;
        #pragma unroll
        for (int s = 0; s < NSPLIT; ++s) {
            wgt[s] = exp2f((mp[g + (long)s * 8000] - mm) * L2E);
            ls += wgt[s] * lp[g + (long)s * 8000];
        }
        const float linv = 1.0f / ls;
        float4 a0 = make_float4(0.f,0.f,0.f,0.f), a1 = make_float4(0.f,0.f,0.f,0.f);
        #pragma unroll
        for (int s = 0; s < NSPLIT; ++s) {
            const float* src = Opart + (long)s * 1024000 + g * 128 + pc;
            float4 p = *(const float4*)src;
            float4 q = *(const float4*)(src + 4);
            a0.x = fmaf(wgt[s], p.x, a0.x); a0.y = fmaf(wgt[s], p.y, a0.y);
            a0.z = fmaf(wgt[s], p.z, a0.z); a0.w = fmaf(wgt[s], p.w, a0.w);
            a1.x = fmaf(wgt[s], q.x, a1.x); a1.y = fmaf(wgt[s], q.y, a1.y);
            a1.z = fmaf(wgt[s], q.z, a1.z); a1.w = fmaf(wgt[s], q.w, a1.w);
        }
        *(float4*)&Xs[pr][pc]     = make_float4(a0.x*linv, a0.y*linv, a0.z*linv, a0.w*linv);
        *(float4*)&Xs[pr][pc + 4] = make_float4(a1.x*linv, a1.y*linv, a1.z*linv, a1.w*linv);
    }
    __syncthreads();                                  // (1) Ws=Wvo, Xs=merged X visible
    float acc[2][4] = {};
    #pragma unroll 8
    for (int kk4 = 0; kk4 < 128; kk4 += 4) {
        float4 xa = *(const float4*)&Xs[r0 + 0][kk4];
        float4 xb = *(const float4*)&Xs[r0 + 1][kk4];
        #pragma unroll
        for (int j = 0; j < 4; ++j) {
            float4 w4 = *(const float4*)&Ws[kk4 + j][c0];
            float x0 = (j==0)?xa.x:(j==1)?xa.y:(j==2)?xa.z:xa.w;
            float x1 = (j==0)?xb.x:(j==1)?xb.y:(j==2)?xb.z:xb.w;
            acc[0][0]=fmaf(x0,w4.x,acc[0][0]); acc[0][1]=fmaf(x0,w4.y,acc[0][1]);
            acc[0][2]=fmaf(x0,w4.z,acc[0][2]); acc[0][3]=fmaf(x0,w4.w,acc[0][3]);
            acc[1][0]=fmaf(x1,w4.x,acc[1][0]); acc[1][1]=fmaf(x1,w4.y,acc[1][1]);
            acc[1][2]=fmaf(x1,w4.z,acc[1][2]); acc[1][3]=fmaf(x1,w4.w,acc[1][3]);
        }
    }
    __syncthreads();                                  // (2) all GEMM1 reads of Ws/Xs done
    #pragma unroll
    for (int u = 0; u < 16; ++u) {
        int s = t + u * 256, r = s >> 5, cb = (s & 31) << 2;
        *(float4*)&Ws[r][cb] = *(const float4*)(jp_w + (long)r * 128 + cb);
    }
    {
        float4 bv = *(const float4*)(bvo + c0);
        #pragma unroll
        for (int i = 0; i < 2; ++i) {
            float4 o = make_float4(acc[i][0]+bv.x, acc[i][1]+bv.y, acc[i][2]+bv.z, acc[i][3]+bv.w);
            int orow = p0 + r0 + i;
            if (orow < LP)
                *(float4*)(PF + ((long)b * LP + orow) * 128 + c0) = o;
            *(float4*)&Xs[r0 + i][c0] =
                make_float4(fmaxf(o.x,0.f), fmaxf(o.y,0.f), fmaxf(o.z,0.f), fmaxf(o.w,0.f));
        }
    }
    __syncthreads();                                  // (3) Ws=jp_w, Xs=relu(PF) visible
    float ac2[2][4] = {};
    #pragma unroll 8
    for (int kk4 = 0; kk4 < 128; kk4 += 4) {
        float4 xa = *(const float4*)&Xs[r0 + 0][kk4];
        float4 xb = *(const float4*)&Xs[r0 + 1][kk4];
        #pragma unroll
        for (int j = 0; j < 4; ++j) {
            float4 w4 = *(const float4*)&Ws[kk4 + j][c0];
            float x0 = (j==0)?xa.x:(j==1)?xa.y:(j==2)?xa.z:xa.w;
            float x1 = (j==0)?xb.x:(j==1)?xb.y:(j==2)?xb.z:xb.w;
            ac2[0][0]=fmaf(x0,w4.x,ac2[0][0]); ac2[0][1]=fmaf(x0,w4.y,ac2[0][1]);
            ac2[0][2]=fmaf(x0,w4.z,ac2[0][2]); ac2[0][3]=fmaf(x0,w4.w,ac2[0][3]);
            ac2[1][0]=fmaf(x1,w4.x,ac2[1][0]); ac2[1][1]=fmaf(x1,w4.y,ac2[1][1]);
            ac2[1][2]=fmaf(x1,w4.z,ac2[1][2]); ac2[1][3]=fmaf(x1,w4.w,ac2[1][3]);
        }
    }
    float4 b2 = *(const float4*)(jp_b + c0);
    #pragma unroll
    for (int i = 0; i < 2; ++i) {
        int orow = p0 + r0 + i;
        if (orow < LP)
            *(float4*)(PJ + ((long)b * LP + orow) * 128 + c0) =
                make_float4(ac2[i][0]+b2.x, ac2[i][1]+b2.y, ac2[i][2]+b2.z, ac2[i][3]+b2.w);
    }
}

// ---------------- mt2: per (16-row tile x 16-compound chunk): sigmoid-A + tanh reduce ----------
// v2: 2016 blocks, ~10.8 KB LDS. Pjs/Pfs LDS staging dropped (L1-broadcast / coalesced global
// reads instead); Cs halved to 16 compounds. Occupancy cap 25% -> ~97% (wave/grid-limited).
template<int IIN>
__device__ __forceinline__ float tanh_chunk(const float (*Cs)[132], const float (*AshT)[20],
                                            const float* areg, int d, int kh)
{
    float accD = 0.f;
    for (int kk = 0; kk < 8; ++kk) {
        const int k = (kh << 3) + kk;
        const float cv = Cs[k][d];
        #pragma unroll
        for (int iq = 0; iq < IIN; iq += 4) {
            float4 a4 = *(const float4*)&AshT[k][iq];
            float e0 = exp2f(areg[iq+0] * cv);
            float e1 = exp2f(areg[iq+1] * cv);
            float e2 = exp2f(areg[iq+2] * cv);
            float e3 = exp2f(areg[iq+3] * cv);
            accD = fmaf(1.f - 2.f * rcp_fast(e0 + 1.f), a4.x, accD);
            accD = fmaf(1.f - 2.f * rcp_fast(e1 + 1.f), a4.y, accD);
            accD = fmaf(1.f - 2.f * rcp_fast(e2 + 1.f), a4.z, accD);
            accD = fmaf(1.f - 2.f * rcp_fast(e3 + 1.f), a4.w, accD);
        }
    }
    return accD;
}

__global__ __launch_bounds__(256) void mt2_k(
    const float* __restrict__ PF, const float* __restrict__ PJ,
    const float* __restrict__ Cj, const float* __restrict__ CF,
    float* __restrict__ Asum, float* __restrict__ cpe)
{
    __shared__ __align__(16) float Cs[16][132];
    __shared__ __align__(16) float AshT[16][20];
    __shared__ float red[256];
    const int t  = threadIdx.x;
    const int p0 = blockIdx.x * 16;
    const int kc = blockIdx.y;            // compound chunk: rows kc*16 .. kc*16+15
    const int b  = blockIdx.z;
    const float L2E = 1.4426950408889634f;

    // stage Cj chunk (16x128) to LDS; prefetch CF chunk into regs
    float4 cfv[2];
    #pragma unroll
    for (int u = 0; u < 2; ++u) {
        int s = t + u * 256, r = s >> 5, cb = (s & 31) << 2;
        *(float4*)&Cs[r][cb] = *(const float4*)(Cj + ((long)b * NCMP + kc * 16 + r) * 128 + cb);
        cfv[u] = *(const float4*)(CF + ((long)b * NCMP + kc * 16 + r) * 128 + cb);
    }
    __syncthreads();
    // S = Pj @ Cs^T (16x16), one element per thread; Pj rows read via L1 broadcast
    const int tr = t >> 4, tc = t & 15;
    int gr = p0 + tr; if (gr > LP - 1) gr = LP - 1;
    const float* pj = PJ + ((long)b * LP + gr) * 128;
    float sacc = 0.f;
    #pragma unroll 8
    for (int d4 = 0; d4 < 32; ++d4) {
        float4 p4 = *(const float4*)(pj + (d4 << 2));
        float4 cv = *(const float4*)&Cs[tc][d4 << 2];
        sacc += p4.x*cv.x + p4.y*cv.y + p4.z*cv.z + p4.w*cv.w;
    }
    float lsum = 0.f;
    if (p0 + tr < LP) {
        float sg = rcp_fast(1.f + exp2f(-sacc * L2E));
        AshT[tc][tr] = sg;
        lsum = sg;
    }
    #pragma unroll
    for (int off = 1; off < 64; off <<= 1) lsum += __shfl_xor(lsum, off);
    if ((t & 63) == 0) red[t >> 6] = lsum;
    __syncthreads();                       // AshT + red visible; Cj reads of Cs done
    if (t == 0) atomicAdd(Asum + b, (red[0] + red[1]) + (red[2] + red[3]));
    #pragma unroll
    for (int u = 0; u < 2; ++u) {          // overwrite Cs with CF chunk
        int s = t + u * 256, r = s >> 5, cb = (s & 31) << 2;
        *(float4*)&Cs[r][cb] = cfv[u];
    }
    __syncthreads();                       // CF visible
    // tanh-weighted reduce over this chunk (areg from global PF, coalesced)
    const float TWO_L2E = 2.8853900817779268f;
    const int d = t & 127, kh = t >> 7;
    float areg[16];
    #pragma unroll
    for (int ii = 0; ii < 16; ++ii) {
        int rr = p0 + ii; if (rr > LP - 1) rr = LP - 1;
        areg[ii] = PF[((long)b * LP + rr) * 128 + d] * TWO_L2E;
    }
    float accD = (p0 + 16 <= LP) ? tanh_chunk<16>(Cs, AshT, areg, d, kh)
                                 : tanh_chunk<8>(Cs, AshT, areg, d, kh);
    red[t] = accD;
    __syncthreads();
    if (t < 128) atomicAdd(cpe + (long)b * 128 + t, red[t] + red[t + 128]);
}

// ---------------- c12: fused c1 slice + c2 split-K partials, 128 blocks ----------------
__global__ __launch_bounds__(256) void c12_k(const float* __restrict__ cpe, const float* __restrict__ Asum,
                                             const float* __restrict__ c1_w, const float* __restrict__ c1_b,
                                             const float* __restrict__ c2_w, float* __restrict__ part)
{
    __shared__ float sc[8][128];
    __shared__ float ins[8][8];
    const int t = threadIdx.x, ks = blockIdx.x, k0 = ks * 8;
    #pragma unroll
    for (int u = 0; u < 4; ++u) {
        int idx = t + u * 256;
        sc[idx >> 7][idx & 127] = cpe[idx] * rcp_fast(Asum[idx >> 7]);
    }
    __syncthreads();
    if (t < 64) {
        int b = t >> 3, kk = t & 7;
        int n1 = k0 + kk;
        float a0 = 0.f, a1 = 0.f, a2 = 0.f, a3 = 0.f;
        #pragma unroll 8
        for (int j = 0; j < 128; j += 4) {
            a0 = fmaf(sc[b][j+0], c1_w[(long)(j+0)*1024 + n1], a0);
            a1 = fmaf(sc[b][j+1], c1_w[(long)(j+1)*1024 + n1], a1);
            a2 = fmaf(sc[b][j+2], c1_w[(long)(j+2)*1024 + n1], a2);
            a3 = fmaf(sc[b][j+3], c1_w[(long)(j+3)*1024 + n1], a3);
        }
        ins[b][kk] = fmaxf((a0 + a1) + (a2 + a3) + c1_b[n1], 0.f);
    }
    __syncthreads();
    const int n = (t & 63) * 4 + (t >> 6) * 256;
    float4 acc[8] = {};
    #pragma unroll
    for (int kk = 0; kk < 8; ++kk) {
        float4 w4 = *(const float4*)(c2_w + (long)(k0 + kk) * 1024 + n);
        #pragma unroll
        for (int b = 0; b < 8; ++b) {
            float s = ins[b][kk];
            acc[b].x = fmaf(s, w4.x, acc[b].x); acc[b].y = fmaf(s, w4.y, acc[b].y);
            acc[b].z = fmaf(s, w4.z, acc[b].z); acc[b].w = fmaf(s, w4.w, acc[b].w);
        }
    }
    #pragma unroll
    for (int b = 0; b < 8; ++b)
        *(float4*)(part + ((long)(ks * 8 + b)) * 1024 + n) = acc[b];
}

// ------- c3+c4 fused -------
__global__ __launch_bounds__(256) void c3m_k(const float* __restrict__ part2, const float* __restrict__ c2_b,
                                             const float* __restrict__ c3_w, const float* __restrict__ c3_b,
                                             const float* __restrict__ c4_w, const float* __restrict__ c4_b,
                                             float* __restrict__ out)
{
    __shared__ float Hs[1024];
    __shared__ float red[256];
    const int t = threadIdx.x, b = blockIdx.x;
    float4 acc4 = make_float4(0.f,0.f,0.f,0.f);
    #pragma unroll 4
    for (int ks = 0; ks < 128; ++ks) {
        float4 p = *(const float4*)(part2 + ((long)(ks * 8 + b)) * 1024 + t * 4);
        acc4.x += p.x; acc4.y += p.y; acc4.z += p.z; acc4.w += p.w;
    }
    {
        float4 bb = *(const float4*)(c2_b + t * 4);
        Hs[t*4+0] = fmaxf(acc4.x + bb.x, 0.f);
        Hs[t*4+1] = fmaxf(acc4.y + bb.y, 0.f);
        Hs[t*4+2] = fmaxf(acc4.z + bb.z, 0.f);
        Hs[t*4+3] = fmaxf(acc4.w + bb.w, 0.f);
    }
    __syncthreads();
    float a0 = 0.f, a1 = 0.f, a2 = 0.f, a3 = 0.f;
    #pragma unroll 8
    for (int k = 0; k < 1024; k += 4) {
        a0 = fmaf(Hs[k+0], c3_w[(long)(k+0)*256 + t], a0);
        a1 = fmaf(Hs[k+1], c3_w[(long)(k+1)*256 + t], a1);
        a2 = fmaf(Hs[k+2], c3_w[(long)(k+2)*256 + t], a2);
        a3 = fmaf(Hs[k+3], c3_w[(long)(k+3)*256 + t], a3);
    }
    float h3v = fmaxf((a0 + a1) + (a2 + a3) + c3_b[t], 0.f);
    red[t] = h3v * c4_w[t];
    __syncthreads();
    for (int off = 128; off > 0; off >>= 1) {
        if (t < off) red[t] += red[t + off];
        __syncthreads();
    }
    if (t == 0) out[b] = red[0] + c4_b[0];
}

extern "C" void kernel_launch(void* const* d_in, const int* in_sizes, int n_in,
                              void* d_out, int out_size, void* d_ws, size_t ws_size,
                              hipStream_t stream)
{
    const float* PE   = (const float*)d_in[0];
    const float* PFX  = (const float*)d_in[1];
    const float* CF   = (const float*)d_in[2];
    const float* emb_w = (const float*)d_in[3];  const float* emb_b = (const float*)d_in[4];
    const float* wq_w  = (const float*)d_in[5];  const float* wq_b  = (const float*)d_in[6];
    const float* wk_w  = (const float*)d_in[7];  const float* wk_b  = (const float*)d_in[8];
    const float* wv_w  = (const float*)d_in[9];  const float* wv_b  = (const float*)d_in[10];
    const float* wo_w  = (const float*)d_in[11]; const float* wo_b  = (const float*)d_in[12];
    const float* jp_w  = (const float*)d_in[13]; const float* jp_b  = (const float*)d_in[14];
    const float* jc_w  = (const float*)d_in[15]; const float* jc_b  = (const float*)d_in[16];
    const float* c1_w  = (const float*)d_in[17]; const float* c1_b  = (const float*)d_in[18];
    const float* c2_w  = (const float*)d_in[19]; const float* c2_b  = (const float*)d_in[20];
    const float* c3_w  = (const float*)d_in[21]; const float* c3_b  = (const float*)d_in[22];
    const float* c4_w  = (const float*)d_in[23]; const float* c4_b  = (const float*)d_in[24];

    float* ws     = (float*)d_ws;
    f16*  Qhi   = (f16*)ws;                        // 8*1024*128 fp16 = 524,288 float-slots
    f16*  Qlo   = (f16*)(ws + 524288);
    f16*  Khi   = (f16*)(ws + 1048576);
    f16*  Klo   = (f16*)(ws + 1572864);
    f16*  Vthi  = (f16*)(ws + 2097152);            // [8][128][1024] fp16
    f16*  Vtlo  = (f16*)(ws + 2621440);
    float* bufC   = ws + 3145728;                  //    65,536 (jc output)
    float* Opart  = bufC + 65536;                  // 4,096,000 (4-way flash partials)
    float* mpart  = Opart + 4096000;               //    32,000
    float* lpart  = mpart + 32000;                 //    32,000
    float* Asum   = lpart + 32000;                 //         8
    float* cpe    = Asum + 8;                      //     1,024
    float* bprime = cpe + 1024;                    //       128
    float* bufWvo = bprime + 128;                  //    16,384 (wv_w @ wo_w)
    float* bufbvo = bufWvo + 16384;                //       128
    float* part2  = ws;                            // c2 partials alias Q/K fp16 region
    float* PFbuf  = ws + 1048576;                  // [8][1000][128] protein_feats (alias K region post-flash)
    float* PJbuf  = ws + 2097152;                  // [8][1000][128] jp output (alias Vt region post-flash)
    // fp16 split weights (beyond main region)
    f16* WpThi = (f16*)(ws + 7430144);             // [128][320] f16 = 20,480 float slots
    f16* WpTlo = (f16*)(ws + 7450624);
    f16* WkThi = (f16*)(ws + 7471104);             // [128][128] f16 = 8,192 float slots
    f16* WkTlo = (f16*)(ws + 7479296);             // end = 7,487,488 floats (~30 MB)

    pre0_k<<<24, 256, 0, stream>>>(emb_w, emb_b, wq_w, wq_b, wk_w, wv_w, wv_b, wo_w, wo_b,
                                   WpThi, WpTlo, WkThi, WkTlo,
                                   bprime, bufWvo, bufbvo, Asum);
    qkv3_k<<<522, 256, 0, stream>>>(PE, PFX, WpThi, WpTlo, WkThi, WkTlo,
                                    bprime, wk_b, CF, jc_w, jc_b,
                                    Qhi, Qlo, Khi, Klo, Vthi, Vtlo, bufC);
    flash7_k<<<dim3(16, NSPLIT, 8), 256, 0, stream>>>(Qhi, Qlo, Khi, Klo, Vthi, Vtlo,
                                                      Opart, mpart, lpart);
    mt1ab_k<<<dim3(63, 8), 256, 0, stream>>>(Opart, mpart, lpart, bufWvo, bufbvo,
                                             jp_w, jp_b, PFbuf, PJbuf);
    mt2_k<<<dim3(63, 4, 8), 256, 0, stream>>>(PFbuf, PJbuf, bufC, CF, Asum, cpe);
    c12_k<<<128, 256, 0, stream>>>(cpe, Asum, c1_w, c1_b, c2_w, part2);
    c3m_k<<<8, 256, 0, stream>>>(part2, c2_b, c3_w, c3_b, c4_w, c4_b, (float*)d_out);
}

// Round 8
// 270.657 us; speedup vs baseline: 1.0946x; 1.0946x over previous
//
#include <hip/hip_runtime.h>
#include <hip/hip_bf16.h>
#include <math.h>

#define LP 1000
#define NCMP 64
#define NSPLIT 4

typedef _Float16 f16;
typedef f16   v8h __attribute__((ext_vector_type(8)));
typedef float v4f __attribute__((ext_vector_type(4)));

__device__ __forceinline__ float rcp_fast(float x) { return __builtin_amdgcn_rcpf(x); }
// raw v_exp_f32 (2^x): skips OCML's denormal-fixup multi-inst path. ~1ulp, flush-to-zero —
// fine for sigmoid/tanh where results saturate.
__device__ __forceinline__ float fexp2(float x) {
#if __has_builtin(__builtin_amdgcn_exp2f)
    return __builtin_amdgcn_exp2f(x);
#else
    float r;
    asm("v_exp_f32 %0, %1" : "=v"(r) : "v"(x));
    return r;
#endif
}
__device__ __forceinline__ void fsplit(float x, f16& h, f16& l) {
    h = (f16)x; l = (f16)(x - (float)h);
}
// fp32x8 -> fp16 hi/lo vectors, in registers (bit-identical to materialized split)
__device__ __forceinline__ void fs8(const float4& f0, const float4& f1, v8h& h, v8h& l) {
    const float x[8] = {f0.x, f0.y, f0.z, f0.w, f1.x, f1.y, f1.z, f1.w};
    #pragma unroll
    for (int i = 0; i < 8; ++i) {
        f16 hh = (f16)x[i];
        h[i] = hh;
        l[i] = (f16)(x[i] - (float)hh);
    }
}

struct H4 { f16 a, b, c, d; };   // 8-byte fp16 quad

// ---------------- GEMM core: Y[M,128] = op(X)[M,K] @ W[K,128] + b ----------------
// 32-row tile, 256 threads, thread 4x4, X transposed in LDS, software-pipelined.
__device__ __forceinline__ void gemm_core(float (*Ws)[128], float (*Xt)[36],
                                          const float* X, const float* W, const float* bias,
                                          float* Y, int K, int rowbase, bool relu_in)
{
    const int t  = threadIdx.x;
    const int r0 = (t >> 5) * 4;
    const int c0 = (t & 31) * 4;
    const int xr = t >> 3, xk = (t & 7) << 2;
    const int xrow = rowbase + xr;
    float4 xv = *(const float4*)(X + (long)xrow * K + xk);
    float4 wv[4];
    #pragma unroll
    for (int u = 0; u < 4; ++u) {
        int s = t + u * 256, r = s >> 5, cb = (s & 31) << 2;
        wv[u] = *(const float4*)(W + (long)r * 128 + cb);
    }
    float acc[4][4] = {};
    for (int k0 = 0; k0 < K; k0 += 32) {
        float4 xs = xv;
        if (relu_in) { xs.x = fmaxf(xs.x,0.f); xs.y = fmaxf(xs.y,0.f);
                       xs.z = fmaxf(xs.z,0.f); xs.w = fmaxf(xs.w,0.f); }
        Xt[xk+0][xr] = xs.x; Xt[xk+1][xr] = xs.y; Xt[xk+2][xr] = xs.z; Xt[xk+3][xr] = xs.w;
        #pragma unroll
        for (int u = 0; u < 4; ++u) {
            int s = t + u * 256, r = s >> 5, cb = (s & 31) << 2;
            *(float4*)&Ws[r][cb] = wv[u];
        }
        __syncthreads();
        if (k0 + 32 < K) {
            xv = *(const float4*)(X + (long)xrow * K + k0 + 32 + xk);
            #pragma unroll
            for (int u = 0; u < 4; ++u) {
                int s = t + u * 256, r = s >> 5, cb = (s & 31) << 2;
                wv[u] = *(const float4*)(W + (long)(k0 + 32 + r) * 128 + cb);
            }
        }
        #pragma unroll
        for (int kk = 0; kk < 32; ++kk) {
            float4 w4 = *(const float4*)&Ws[kk][c0];
            float4 x4 = *(const float4*)&Xt[kk][r0];
            acc[0][0] = fmaf(x4.x, w4.x, acc[0][0]); acc[0][1] = fmaf(x4.x, w4.y, acc[0][1]);
            acc[0][2] = fmaf(x4.x, w4.z, acc[0][2]); acc[0][3] = fmaf(x4.x, w4.w, acc[0][3]);
            acc[1][0] = fmaf(x4.y, w4.x, acc[1][0]); acc[1][1] = fmaf(x4.y, w4.y, acc[1][1]);
            acc[1][2] = fmaf(x4.y, w4.z, acc[1][2]); acc[1][3] = fmaf(x4.y, w4.w, acc[1][3]);
            acc[2][0] = fmaf(x4.z, w4.x, acc[2][0]); acc[2][1] = fmaf(x4.z, w4.y, acc[2][1]);
            acc[2][2] = fmaf(x4.z, w4.z, acc[2][2]); acc[2][3] = fmaf(x4.z, w4.w, acc[2][3]);
            acc[3][0] = fmaf(x4.w, w4.x, acc[3][0]); acc[3][1] = fmaf(x4.w, w4.y, acc[3][1]);
            acc[3][2] = fmaf(x4.w, w4.z, acc[3][2]); acc[3][3] = fmaf(x4.w, w4.w, acc[3][3]);
        }
        __syncthreads();
    }
    float4 bv = bias ? *(const float4*)(bias + c0) : make_float4(0.f,0.f,0.f,0.f);
    #pragma unroll
    for (int i = 0; i < 4; ++i) {
        int row = rowbase + r0 + i;
        float4 o;
        o.x = acc[i][0] + bv.x; o.y = acc[i][1] + bv.y;
        o.z = acc[i][2] + bv.z; o.w = acc[i][3] + bv.w;
        *(float4*)(Y + (long)row * 128 + c0) = o;
    }
}

// Same GEMM but epilogue writes the TRANSPOSED fp16 hi/lo split: T[n][k] for Y[k][n].
__device__ __forceinline__ void gemm_coreT(float (*Ws)[128], float (*Xt)[36],
                                           const float* X, const float* W,
                                           f16* ThT, f16* TlT, int KT, int rowbase)
{
    const int t  = threadIdx.x;
    const int r0 = (t >> 5) * 4;
    const int c0 = (t & 31) * 4;
    const int xr = t >> 3, xk = (t & 7) << 2;
    const int xrow = rowbase + xr;
    float4 xv = *(const float4*)(X + (long)xrow * 128 + xk);
    float4 wv[4];
    #pragma unroll
    for (int u = 0; u < 4; ++u) {
        int s = t + u * 256, r = s >> 5, cb = (s & 31) << 2;
        wv[u] = *(const float4*)(W + (long)r * 128 + cb);
    }
    float acc[4][4] = {};
    for (int k0 = 0; k0 < 128; k0 += 32) {
        Xt[xk+0][xr] = xv.x; Xt[xk+1][xr] = xv.y; Xt[xk+2][xr] = xv.z; Xt[xk+3][xr] = xv.w;
        #pragma unroll
        for (int u = 0; u < 4; ++u) {
            int s = t + u * 256, r = s >> 5, cb = (s & 31) << 2;
            *(float4*)&Ws[r][cb] = wv[u];
        }
        __syncthreads();
        if (k0 + 32 < 128) {
            xv = *(const float4*)(X + (long)xrow * 128 + k0 + 32 + xk);
            #pragma unroll
            for (int u = 0; u < 4; ++u) {
                int s = t + u * 256, r = s >> 5, cb = (s & 31) << 2;
                wv[u] = *(const float4*)(W + (long)(k0 + 32 + r) * 128 + cb);
            }
        }
        #pragma unroll
        for (int kk = 0; kk < 32; ++kk) {
            float4 w4 = *(const float4*)&Ws[kk][c0];
            float4 x4 = *(const float4*)&Xt[kk][r0];
            acc[0][0] = fmaf(x4.x, w4.x, acc[0][0]); acc[0][1] = fmaf(x4.x, w4.y, acc[0][1]);
            acc[0][2] = fmaf(x4.x, w4.z, acc[0][2]); acc[0][3] = fmaf(x4.x, w4.w, acc[0][3]);
            acc[1][0] = fmaf(x4.y, w4.x, acc[1][0]); acc[1][1] = fmaf(x4.y, w4.y, acc[1][1]);
            acc[1][2] = fmaf(x4.y, w4.z, acc[1][2]); acc[1][3] = fmaf(x4.y, w4.w, acc[1][3]);
            acc[2][0] = fmaf(x4.z, w4.x, acc[2][0]); acc[2][1] = fmaf(x4.z, w4.y, acc[2][1]);
            acc[2][2] = fmaf(x4.z, w4.z, acc[2][2]); acc[2][3] = fmaf(x4.z, w4.w, acc[2][3]);
            acc[3][0] = fmaf(x4.w, w4.x, acc[3][0]); acc[3][1] = fmaf(x4.w, w4.y, acc[3][1]);
            acc[3][2] = fmaf(x4.w, w4.z, acc[3][2]); acc[3][3] = fmaf(x4.w, w4.w, acc[3][3]);
        }
        __syncthreads();
    }
    // transposed split epilogue: T[col][rowK], rowK in [0,KT)
    #pragma unroll
    for (int i = 0; i < 4; ++i) {
        int row = rowbase + r0 + i;
        #pragma unroll
        for (int j = 0; j < 4; ++j) {
            f16 h, l; fsplit(acc[i][j], h, l);
            long o = (long)(c0 + j) * KT + row;
            ThT[o] = h; TlT[o] = l;
        }
    }
}

// ---- pre0b: 0-9: Wp=emb_w@wq_w -> WpT hi/lo (transposed split, no fp32 Wp);
//      10: bp + zero Asum/cpe; 11-14: Wvo=wv_w@wo_w; 15: bvo; 16-23: wk_w -> WkT hi/lo ----
__global__ __launch_bounds__(256) void pre0_k(const float* __restrict__ emb_w, const float* __restrict__ emb_b,
                                              const float* __restrict__ wq_w, const float* __restrict__ wq_b,
                                              const float* __restrict__ wk_w,
                                              const float* __restrict__ wv_w, const float* __restrict__ wv_b,
                                              const float* __restrict__ wo_w, const float* __restrict__ wo_b,
                                              f16* __restrict__ WpThi, f16* __restrict__ WpTlo,
                                              f16* __restrict__ WkThi, f16* __restrict__ WkTlo,
                                              float* __restrict__ bp,
                                              float* __restrict__ Wvo, float* __restrict__ bvo,
                                              float* __restrict__ zbase)
{
    __shared__ __align__(16) float Ws[32][128];
    __shared__ __align__(16) float Xt[32][36];
    const int bid = blockIdx.x;
    const int t = threadIdx.x;
    if (bid < 10) { gemm_coreT(Ws, Xt, emb_w, wq_w, WpThi, WpTlo, 320, bid * 32); return; }
    if (bid >= 11 && bid < 15) { gemm_core(Ws, Xt, wv_w, wo_w, nullptr, Wvo, 128, (bid - 11) * 32, false); return; }
    if (bid >= 16) {
        // wk_w [128][128] -> WkT hi/lo [n][k]; 8 blocks x 2048 elems
        #pragma unroll
        for (int u = 0; u < 8; ++u) {
            int idx = (bid - 16) * 2048 + u * 256 + t;
            int k = idx >> 7, n = idx & 127;
            f16 h, l; fsplit(wk_w[idx], h, l);
            WkThi[(long)n * 128 + k] = h; WkTlo[(long)n * 128 + k] = l;
        }
        return;
    }
    if (bid == 10 && t >= 128) {
        for (int i = t - 128; i < 1032; i += 128) zbase[i] = 0.f;
        return;
    }
    if (t < 128) {
        const float* vb = (bid == 10) ? emb_b : wv_b;
        const float* Wm = (bid == 10) ? wq_w  : wo_w;
        const float* ab = (bid == 10) ? wq_b  : wo_b;
        float a0 = 0.f, a1 = 0.f, a2 = 0.f, a3 = 0.f;
        for (int k = 0; k < 128; k += 4) {
            a0 = fmaf(vb[k+0], Wm[(k+0)*128 + t], a0);
            a1 = fmaf(vb[k+1], Wm[(k+1)*128 + t], a1);
            a2 = fmaf(vb[k+2], Wm[(k+2)*128 + t], a2);
            a3 = fmaf(vb[k+3], Wm[(k+3)*128 + t], a3);
        }
        float* dst = (bid == 10) ? bp : bvo;
        dst[t] = (a0 + a1) + (a2 + a3) + ab[t];
    }
}

// ---- qkv3b: split-fp16 MFMA GEMM for Q (K=320) and K (K=128) + Cj + V^T split. ----
// 0-127: Q tiles; 128-255: K tiles; 256-271: Cj (scalar gemm_core); 272-521: V^T hi/lo split.
__global__ __launch_bounds__(256) void qkv3_k(
    const float* __restrict__ PE, const float* __restrict__ PFX,
    const f16* __restrict__ WpThi, const f16* __restrict__ WpTlo,
    const f16* __restrict__ WkThi, const f16* __restrict__ WkTlo,
    const float* __restrict__ bp, const float* __restrict__ wk_b,
    const float* __restrict__ CF, const float* __restrict__ jc_w, const float* __restrict__ jc_b,
    f16* __restrict__ Qhi, f16* __restrict__ Qlo,
    f16* __restrict__ Khi, f16* __restrict__ Klo,
    f16* __restrict__ Vthi, f16* __restrict__ Vtlo,
    float* __restrict__ Cj)
{
    __shared__ __align__(16) float Ws[32][128];
    __shared__ __align__(16) float Xt[32][36];
    const int bid = blockIdx.x;
    const int t = threadIdx.x;
    if (bid >= 272) {
        // V^T split (V = raw PFX), [b][d][1024] fp16 hi/lo
        const int rb = (bid - 272) * 32;
        const int d = t >> 1, half = t & 1;
        #pragma unroll 4
        for (int i = 0; i < 16; ++i) {
            int row = rb + half * 16 + i;
            int bb = row / 1000, rr = row - bb * 1000;
            float v = PFX[(long)row * 128 + d];
            f16 h, l; fsplit(v, h, l);
            long o = ((long)bb * 128 + d) * 1024 + rr;
            Vthi[o] = h; Vtlo[o] = l;
        }
        return;
    }
    if (bid >= 256) { gemm_core(Ws, Xt, CF, jc_w, jc_b, Cj, 128, (bid - 256) * 32, true); return; }
    const bool isQ = bid < 128;
    const int b = (bid & 127) >> 4, tile = bid & 15;
    const int KD  = isQ ? 320 : 128;
    const int NCH = isQ ? 10 : 4;
    const float* A = isQ ? PE : PFX;
    const f16* Bhi = isQ ? WpThi : WkThi;
    const f16* Blo = isQ ? WpTlo : WkTlo;
    const float* bias = isQ ? bp : wk_b;
    f16* Yhi = isQ ? Qhi : Khi;
    f16* Ylo = isQ ? Qlo : Klo;

    const int wv = t >> 6, lane = t & 63, quad = lane >> 4, l4 = lane & 15;
    int arow = tile * 64 + wv * 16 + l4; if (arow >= LP) arow = LP - 1;
    const float* a_p = A + ((long)b * LP + arow) * KD;

    v4f acc[8];
    #pragma unroll
    for (int dt = 0; dt < 8; ++dt) acc[dt] = (v4f){0.f, 0.f, 0.f, 0.f};

    for (int kt = 0; kt < NCH; ++kt) {
        const int ko = kt * 32 + quad * 8;
        float4 f0 = *(const float4*)(a_p + ko);
        float4 f1 = *(const float4*)(a_p + ko + 4);
        v8h ah, al;
        fs8(f0, f1, ah, al);
        #pragma unroll
        for (int dt = 0; dt < 8; ++dt) {
            const long bo = (long)(dt * 16 + l4) * KD + ko;
            v8h bh = *(const v8h*)(Bhi + bo);
            v8h bl = *(const v8h*)(Blo + bo);
            acc[dt] = __builtin_amdgcn_mfma_f32_16x16x32_f16(ah, bh, acc[dt], 0, 0, 0);
            acc[dt] = __builtin_amdgcn_mfma_f32_16x16x32_f16(ah, bl, acc[dt], 0, 0, 0);
            acc[dt] = __builtin_amdgcn_mfma_f32_16x16x32_f16(al, bh, acc[dt], 0, 0, 0);
        }
    }
    // epilogue: C-layout (row = tile*64 + wv*16 + quad*4 + r, col = dt*16 + l4)
    #pragma unroll
    for (int dt = 0; dt < 8; ++dt) {
        const int col = dt * 16 + l4;
        const float bv = bias[col];
        #pragma unroll
        for (int r = 0; r < 4; ++r) {
            int row = tile * 64 + wv * 16 + quad * 4 + r;
            long o = ((long)b * 1024 + row) * 128 + col;
            f16 h, l; fsplit(acc[dt][r] + bv, h, l);
            Yhi[o] = h; Ylo[o] = l;
        }
    }
}

// ---------------- flash7: split-fp16 MFMA flash. TQ=64 (4 waves x 16-row band), TK=64 ----------
__global__ __launch_bounds__(256) void flash7_k(const f16* __restrict__ Qhi, const f16* __restrict__ Qlo,
                                                const f16* __restrict__ Khi, const f16* __restrict__ Klo,
                                                const f16* __restrict__ Vthi, const f16* __restrict__ Vtlo,
                                                float* __restrict__ Opart,
                                                float* __restrict__ mpart, float* __restrict__ lpart)
{
    __shared__ __align__(16) f16 KVhi[9216];     // K: [64][136] (<=8704) ; V^T: [128][72] (9216)
    __shared__ __align__(16) f16 KVlo[9216];
    __shared__ __align__(16) f16 Pshi[4][16 * 72];
    __shared__ __align__(16) f16 Pslo[4][16 * 72];
    const int t    = threadIdx.x;
    const int wv   = t >> 6;
    const int lane = t & 63;
    const int quad = lane >> 4;
    const int l4   = lane & 15;
    const int qt = blockIdx.x, sp = blockIdx.y, b = blockIdx.z;
    const int q0 = qt * 64;
    const float SCALE = 0.08838834764831845f;    // 1/sqrt(128)
    const float L2E   = 1.4426950408889634f;

    int qrow = q0 + wv * 16 + l4; if (qrow >= LP) qrow = LP - 1;
    const long qbase = ((long)b * 1024 + qrow) * 128;
    v8h qh[4], ql[4];
    #pragma unroll
    for (int kt4 = 0; kt4 < 4; ++kt4) {
        qh[kt4] = *(const v8h*)(Qhi + qbase + kt4 * 32 + quad * 8);
        ql[kt4] = *(const v8h*)(Qlo + qbase + kt4 * 32 + quad * 8);
    }
    float m_i[4] = { -3.0e38f, -3.0e38f, -3.0e38f, -3.0e38f };
    float l_i[4] = { 0.f, 0.f, 0.f, 0.f };
    v4f  O[8];
    #pragma unroll
    for (int dt = 0; dt < 8; ++dt) O[dt] = (v4f){0.f, 0.f, 0.f, 0.f};

    for (int kt = sp * 4; kt < sp * 4 + 4; ++kt) {
        const int key0 = kt * 64;
        __syncthreads();                              // (A) prev PV done with KV buffers
        #pragma unroll
        for (int u = 0; u < 4; ++u) {                 // stage K hi/lo (64x128 fp16 each)
            int ch = t + u * 256;
            int r = ch >> 4, co = (ch & 15) * 8;
            long ga = ((long)b * 1024 + key0 + r) * 128 + co;
            *(v8h*)(KVhi + r * 136 + co) = *(const v8h*)(Khi + ga);
            *(v8h*)(KVlo + r * 136 + co) = *(const v8h*)(Klo + ga);
        }
        __syncthreads();                              // (B) K visible
        v8h vh[4], vl[4];
        #pragma unroll
        for (int u = 0; u < 4; ++u) {                 // V^T prefetch (in flight under QK)
            int ch = t + u * 256;
            int d = ch >> 3, co = (ch & 7) * 8;
            long ga = ((long)b * 128 + d) * 1024 + key0 + co;
            vh[u] = *(const v8h*)(Vthi + ga);
            vl[u] = *(const v8h*)(Vtlo + ga);
        }
        // ---- QK^T ----
        v4f S[4];
        #pragma unroll
        for (int nt = 0; nt < 4; ++nt) S[nt] = (v4f){0.f, 0.f, 0.f, 0.f};
        #pragma unroll
        for (int nt = 0; nt < 4; ++nt) {
            const int rb = (nt * 16 + l4) * 136;
            #pragma unroll
            for (int kt4 = 0; kt4 < 4; ++kt4) {
                v8h bh = *(const v8h*)(KVhi + rb + kt4 * 32 + quad * 8);
                v8h bl = *(const v8h*)(KVlo + rb + kt4 * 32 + quad * 8);
                S[nt] = __builtin_amdgcn_mfma_f32_16x16x32_f16(qh[kt4], bh, S[nt], 0, 0, 0);
                S[nt] = __builtin_amdgcn_mfma_f32_16x16x32_f16(qh[kt4], bl, S[nt], 0, 0, 0);
                S[nt] = __builtin_amdgcn_mfma_f32_16x16x32_f16(ql[kt4], bh, S[nt], 0, 0, 0);
            }
        }
        #pragma unroll
        for (int nt = 0; nt < 4; ++nt) {
            bool valid = (key0 + nt * 16 + l4) < LP;
            #pragma unroll
            for (int r = 0; r < 4; ++r)
                S[nt][r] = valid ? S[nt][r] * SCALE : -3.0e38f;
        }
        float alpha[4];
        #pragma unroll
        for (int r = 0; r < 4; ++r) {
            float tm = fmaxf(fmaxf(S[0][r], S[1][r]), fmaxf(S[2][r], S[3][r]));
            tm = fmaxf(tm, __shfl_xor(tm, 1));
            tm = fmaxf(tm, __shfl_xor(tm, 2));
            tm = fmaxf(tm, __shfl_xor(tm, 4));
            tm = fmaxf(tm, __shfl_xor(tm, 8));
            float mnew = fmaxf(m_i[r], tm);
            alpha[r] = exp2f((m_i[r] - mnew) * L2E);
            float ps = 0.f;
            #pragma unroll
            for (int nt = 0; nt < 4; ++nt) {
                float p = exp2f((S[nt][r] - mnew) * L2E);
                S[nt][r] = p;
                ps += p;
            }
            ps += __shfl_xor(ps, 1);
            ps += __shfl_xor(ps, 2);
            ps += __shfl_xor(ps, 4);
            ps += __shfl_xor(ps, 8);
            l_i[r] = l_i[r] * alpha[r] + ps;
            m_i[r] = mnew;
        }
        #pragma unroll
        for (int dt = 0; dt < 8; ++dt) {
            O[dt][0] *= alpha[0]; O[dt][1] *= alpha[1];
            O[dt][2] *= alpha[2]; O[dt][3] *= alpha[3];
        }
        __syncthreads();                              // (C) QK reads of KV done
        #pragma unroll
        for (int u = 0; u < 4; ++u) {                 // V regs -> LDS (overwrite K)
            int ch = t + u * 256;
            int d = ch >> 3, co = (ch & 7) * 8;
            *(v8h*)(KVhi + d * 72 + co) = vh[u];
            *(v8h*)(KVlo + d * 72 + co) = vl[u];
        }
        #pragma unroll
        for (int nt = 0; nt < 4; ++nt) {
            int col = nt * 16 + l4;
            #pragma unroll
            for (int r = 0; r < 4; ++r) {
                f16 ph, pl; fsplit(S[nt][r], ph, pl);
                Pshi[wv][(quad * 4 + r) * 72 + col] = ph;
                Pslo[wv][(quad * 4 + r) * 72 + col] = pl;
            }
        }
        __syncthreads();                              // (D) V visible
        // ---- PV ----
        #pragma unroll
        for (int kc = 0; kc < 2; ++kc) {
            v8h pah = *(const v8h*)(Pshi[wv] + l4 * 72 + kc * 32 + quad * 8);
            v8h pal = *(const v8h*)(Pslo[wv] + l4 * 72 + kc * 32 + quad * 8);
            #pragma unroll
            for (int dt = 0; dt < 8; ++dt) {
                v8h vfh = *(const v8h*)(KVhi + (dt * 16 + l4) * 72 + kc * 32 + quad * 8);
                v8h vfl = *(const v8h*)(KVlo + (dt * 16 + l4) * 72 + kc * 32 + quad * 8);
                O[dt] = __builtin_amdgcn_mfma_f32_16x16x32_f16(pah, vfh, O[dt], 0, 0, 0);
                O[dt] = __builtin_amdgcn_mfma_f32_16x16x32_f16(pah, vfl, O[dt], 0, 0, 0);
                O[dt] = __builtin_amdgcn_mfma_f32_16x16x32_f16(pal, vfh, O[dt], 0, 0, 0);
            }
        }
    }
    #pragma unroll
    for (int r = 0; r < 4; ++r) {
        int row = q0 + wv * 16 + quad * 4 + r;
        if (row < LP) {
            long base = (long)sp * 1024000 + ((long)b * LP + row) * 128;
            #pragma unroll
            for (int dt = 0; dt < 8; ++dt)
                Opart[base + dt * 16 + l4] = O[dt][r];
            if (l4 == 0) {
                mpart[(long)sp * 8000 + b * LP + row] = m_i[r];
                lpart[(long)sp * 8000 + b * LP + row] = l_i[r];
            }
        }
    }
}

// ---------------- mt1ab: NSPLIT merge + wo GEMM + jp GEMM, fused, 3 barriers total ----------
__global__ __launch_bounds__(256) void mt1ab_k(
    const float* __restrict__ Opart, const float* __restrict__ mp, const float* __restrict__ lp,
    const float* __restrict__ Wvo, const float* __restrict__ bvo,
    const float* __restrict__ jp_w, const float* __restrict__ jp_b,
    float* __restrict__ PF, float* __restrict__ PJ)
{
    __shared__ __align__(16) float Ws[128][128];   // 64 KB
    __shared__ __align__(16) float Xs[16][132];
    const int t  = threadIdx.x;
    const int p0 = blockIdx.x * 16;
    const int b  = blockIdx.y;
    const float L2E = 1.4426950408889634f;
    const int r0 = (t >> 5) * 2;
    const int c0 = (t & 31) * 4;

    #pragma unroll
    for (int u = 0; u < 16; ++u) {
        int s = t + u * 256, r = s >> 5, cb = (s & 31) << 2;
        *(float4*)&Ws[r][cb] = *(const float4*)(Wvo + (long)r * 128 + cb);
    }
    {
        const int pr = t >> 4, pc = (t & 15) << 3;
        int grow = p0 + pr; if (grow > LP - 1) grow = LP - 1;
        const long g = (long)b * LP + grow;
        float mm = -3.0e38f;
        #pragma unroll
        for (int s = 0; s < NSPLIT; ++s) mm = fmaxf(mm, mp[g + (long)s * 8000]);
        float wgt[NSPLIT]; float ls = 0.f;
        #pragma unroll
        for (int s = 0; s < NSPLIT; ++s) {
            wgt[s] = exp2f((mp[g + (long)s * 8000] - mm) * L2E);
            ls += wgt[s] * lp[g + (long)s * 8000];
        }
        const float linv = 1.0f / ls;
        float4 a0 = make_float4(0.f,0.f,0.f,0.f), a1 = make_float4(0.f,0.f,0.f,0.f);
        #pragma unroll
        for (int s = 0; s < NSPLIT; ++s) {
            const float* src = Opart + (long)s * 1024000 + g * 128 + pc;
            float4 p = *(const float4*)src;
            float4 q = *(const float4*)(src + 4);
            a0.x = fmaf(wgt[s], p.x, a0.x); a0.y = fmaf(wgt[s], p.y, a0.y);
            a0.z = fmaf(wgt[s], p.z, a0.z); a0.w = fmaf(wgt[s], p.w, a0.w);
            a1.x = fmaf(wgt[s], q.x, a1.x); a1.y = fmaf(wgt[s], q.y, a1.y);
            a1.z = fmaf(wgt[s], q.z, a1.z); a1.w = fmaf(wgt[s], q.w, a1.w);
        }
        *(float4*)&Xs[pr][pc]     = make_float4(a0.x*linv, a0.y*linv, a0.z*linv, a0.w*linv);
        *(float4*)&Xs[pr][pc + 4] = make_float4(a1.x*linv, a1.y*linv, a1.z*linv, a1.w*linv);
    }
    __syncthreads();                                  // (1) Ws=Wvo, Xs=merged X visible
    float acc[2][4] = {};
    #pragma unroll 8
    for (int kk4 = 0; kk4 < 128; kk4 += 4) {
        float4 xa = *(const float4*)&Xs[r0 + 0][kk4];
        float4 xb = *(const float4*)&Xs[r0 + 1][kk4];
        #pragma unroll
        for (int j = 0; j < 4; ++j) {
            float4 w4 = *(const float4*)&Ws[kk4 + j][c0];
            float x0 = (j==0)?xa.x:(j==1)?xa.y:(j==2)?xa.z:xa.w;
            float x1 = (j==0)?xb.x:(j==1)?xb.y:(j==2)?xb.z:xb.w;
            acc[0][0]=fmaf(x0,w4.x,acc[0][0]); acc[0][1]=fmaf(x0,w4.y,acc[0][1]);
            acc[0][2]=fmaf(x0,w4.z,acc[0][2]); acc[0][3]=fmaf(x0,w4.w,acc[0][3]);
            acc[1][0]=fmaf(x1,w4.x,acc[1][0]); acc[1][1]=fmaf(x1,w4.y,acc[1][1]);
            acc[1][2]=fmaf(x1,w4.z,acc[1][2]); acc[1][3]=fmaf(x1,w4.w,acc[1][3]);
        }
    }
    __syncthreads();                                  // (2) all GEMM1 reads of Ws/Xs done
    #pragma unroll
    for (int u = 0; u < 16; ++u) {
        int s = t + u * 256, r = s >> 5, cb = (s & 31) << 2;
        *(float4*)&Ws[r][cb] = *(const float4*)(jp_w + (long)r * 128 + cb);
    }
    {
        float4 bv = *(const float4*)(bvo + c0);
        #pragma unroll
        for (int i = 0; i < 2; ++i) {
            float4 o = make_float4(acc[i][0]+bv.x, acc[i][1]+bv.y, acc[i][2]+bv.z, acc[i][3]+bv.w);
            int orow = p0 + r0 + i;
            if (orow < LP)
                *(float4*)(PF + ((long)b * LP + orow) * 128 + c0) = o;
            *(float4*)&Xs[r0 + i][c0] =
                make_float4(fmaxf(o.x,0.f), fmaxf(o.y,0.f), fmaxf(o.z,0.f), fmaxf(o.w,0.f));
        }
    }
    __syncthreads();                                  // (3) Ws=jp_w, Xs=relu(PF) visible
    float ac2[2][4] = {};
    #pragma unroll 8
    for (int kk4 = 0; kk4 < 128; kk4 += 4) {
        float4 xa = *(const float4*)&Xs[r0 + 0][kk4];
        float4 xb = *(const float4*)&Xs[r0 + 1][kk4];
        #pragma unroll
        for (int j = 0; j < 4; ++j) {
            float4 w4 = *(const float4*)&Ws[kk4 + j][c0];
            float x0 = (j==0)?xa.x:(j==1)?xa.y:(j==2)?xa.z:xa.w;
            float x1 = (j==0)?xb.x:(j==1)?xb.y:(j==2)?xb.z:xb.w;
            ac2[0][0]=fmaf(x0,w4.x,ac2[0][0]); ac2[0][1]=fmaf(x0,w4.y,ac2[0][1]);
            ac2[0][2]=fmaf(x0,w4.z,ac2[0][2]); ac2[0][3]=fmaf(x0,w4.w,ac2[0][3]);
            ac2[1][0]=fmaf(x1,w4.x,ac2[1][0]); ac2[1][1]=fmaf(x1,w4.y,ac2[1][1]);
            ac2[1][2]=fmaf(x1,w4.z,ac2[1][2]); ac2[1][3]=fmaf(x1,w4.w,ac2[1][3]);
        }
    }
    float4 b2 = *(const float4*)(jp_b + c0);
    #pragma unroll
    for (int i = 0; i < 2; ++i) {
        int orow = p0 + r0 + i;
        if (orow < LP)
            *(float4*)(PJ + ((long)b * LP + orow) * 128 + c0) =
                make_float4(ac2[i][0]+b2.x, ac2[i][1]+b2.y, ac2[i][2]+b2.z, ac2[i][3]+b2.w);
    }
}

// ---------------- mt2: per (16-row tile x 32-compound chunk): sigmoid-A + tanh reduce ----------
// R6 structure (Pjs/Pfs/Cs staged in LDS, grid 63x2x8) + raw v_exp_f32 in the hot loops.
template<int IIN>
__device__ __forceinline__ float tanh_chunk(const float (*Cs)[132], const float (*AshT)[20],
                                            const float* areg, int d, int kh)
{
    float accD = 0.f;
    for (int kk = 0; kk < 16; ++kk) {
        const int k = (kh << 4) + kk;
        const float cv = Cs[k][d];
        #pragma unroll
        for (int iq = 0; iq < IIN; iq += 4) {
            float4 a4 = *(const float4*)&AshT[k][iq];
            float e0 = fexp2(areg[iq+0] * cv);
            float e1 = fexp2(areg[iq+1] * cv);
            float e2 = fexp2(areg[iq+2] * cv);
            float e3 = fexp2(areg[iq+3] * cv);
            accD = fmaf(1.f - 2.f * rcp_fast(e0 + 1.f), a4.x, accD);
            accD = fmaf(1.f - 2.f * rcp_fast(e1 + 1.f), a4.y, accD);
            accD = fmaf(1.f - 2.f * rcp_fast(e2 + 1.f), a4.z, accD);
            accD = fmaf(1.f - 2.f * rcp_fast(e3 + 1.f), a4.w, accD);
        }
    }
    return accD;
}

__global__ __launch_bounds__(256) void mt2_k(
    const float* __restrict__ PF, const float* __restrict__ PJ,
    const float* __restrict__ Cj, const float* __restrict__ CF,
    float* __restrict__ Asum, float* __restrict__ cpe)
{
    __shared__ __align__(16) float Pjs[16][132];
    __shared__ __align__(16) float Pfs[16][132];
    __shared__ __align__(16) float Cs[32][132];
    __shared__ __align__(16) float AshT[32][20];
    __shared__ float red[256];
    const int t  = threadIdx.x;
    const int p0 = blockIdx.x * 16;
    const int kc = blockIdx.y;
    const int b  = blockIdx.z;
    const float L2E = 1.4426950408889634f;

    {
        int pr = t >> 4, pc = (t & 15) << 3;
        int gr = p0 + pr; if (gr > LP - 1) gr = LP - 1;
        long gb = ((long)b * LP + gr) * 128 + pc;
        *(float4*)&Pjs[pr][pc]     = *(const float4*)(PJ + gb);
        *(float4*)&Pjs[pr][pc + 4] = *(const float4*)(PJ + gb + 4);
        *(float4*)&Pfs[pr][pc]     = *(const float4*)(PF + gb);
        *(float4*)&Pfs[pr][pc + 4] = *(const float4*)(PF + gb + 4);
    }
    float4 cfv[4];
    #pragma unroll
    for (int u = 0; u < 4; ++u) {
        int s = t + u * 256, r = s >> 5, cb = (s & 31) << 2;
        *(float4*)&Cs[r][cb] = *(const float4*)(Cj + ((long)b * NCMP + kc * 32 + r) * 128 + cb);
        cfv[u] = *(const float4*)(CF + ((long)b * NCMP + kc * 32 + r) * 128 + cb);
    }
    __syncthreads();
    const int tr = t >> 4, tc = t & 15;
    float sacc[2] = {0.f, 0.f};
    #pragma unroll 4
    for (int d4 = 0; d4 < 32; ++d4) {
        float4 p4 = *(const float4*)&Pjs[tr][d4 << 2];
        #pragma unroll
        for (int j = 0; j < 2; ++j) {
            float4 cv = *(const float4*)&Cs[tc + (j << 4)][d4 << 2];
            sacc[j] += p4.x*cv.x + p4.y*cv.y + p4.z*cv.z + p4.w*cv.w;
        }
    }
    float lsum = 0.f;
    const int gi = p0 + tr;
    #pragma unroll
    for (int j = 0; j < 2; ++j) {
        float sg = rcp_fast(1.f + fexp2(-sacc[j] * L2E));
        if (gi < LP) { AshT[tc + (j << 4)][tr] = sg; lsum += sg; }
    }
    #pragma unroll
    for (int off = 1; off < 64; off <<= 1) lsum += __shfl_xor(lsum, off);
    if ((t & 63) == 0) red[t >> 6] = lsum;
    __syncthreads();
    if (t == 0) atomicAdd(Asum + b, (red[0] + red[1]) + (red[2] + red[3]));
    #pragma unroll
    for (int u = 0; u < 4; ++u) {
        int s = t + u * 256, r = s >> 5, cb = (s & 31) << 2;
        *(float4*)&Cs[r][cb] = cfv[u];
    }
    __syncthreads();
    const float TWO_L2E = 2.8853900817779268f;
    const int d = t & 127, kh = t >> 7;
    float areg[16];
    #pragma unroll
    for (int ii = 0; ii < 16; ++ii) areg[ii] = Pfs[ii][d] * TWO_L2E;
    float accD = (p0 + 16 <= LP) ? tanh_chunk<16>(Cs, AshT, areg, d, kh)
                                 : tanh_chunk<8>(Cs, AshT, areg, d, kh);
    red[t] = accD;
    __syncthreads();
    if (t < 128) atomicAdd(cpe + (long)b * 128 + t, red[t] + red[t + 128]);
}

// ---------------- c12: fused c1 slice + c2 split-K partials, 128 blocks ----------------
__global__ __launch_bounds__(256) void c12_k(const float* __restrict__ cpe, const float* __restrict__ Asum,
                                             const float* __restrict__ c1_w, const float* __restrict__ c1_b,
                                             const float* __restrict__ c2_w, float* __restrict__ part)
{
    __shared__ float sc[8][128];
    __shared__ float ins[8][8];
    const int t = threadIdx.x, ks = blockIdx.x, k0 = ks * 8;
    #pragma unroll
    for (int u = 0; u < 4; ++u) {
        int idx = t + u * 256;
        sc[idx >> 7][idx & 127] = cpe[idx] * rcp_fast(Asum[idx >> 7]);
    }
    __syncthreads();
    if (t < 64) {
        int b = t >> 3, kk = t & 7;
        int n1 = k0 + kk;
        float a0 = 0.f, a1 = 0.f, a2 = 0.f, a3 = 0.f;
        #pragma unroll 8
        for (int j = 0; j < 128; j += 4) {
            a0 = fmaf(sc[b][j+0], c1_w[(long)(j+0)*1024 + n1], a0);
            a1 = fmaf(sc[b][j+1], c1_w[(long)(j+1)*1024 + n1], a1);
            a2 = fmaf(sc[b][j+2], c1_w[(long)(j+2)*1024 + n1], a2);
            a3 = fmaf(sc[b][j+3], c1_w[(long)(j+3)*1024 + n1], a3);
        }
        ins[b][kk] = fmaxf((a0 + a1) + (a2 + a3) + c1_b[n1], 0.f);
    }
    __syncthreads();
    const int n = (t & 63) * 4 + (t >> 6) * 256;
    float4 acc[8] = {};
    #pragma unroll
    for (int kk = 0; kk < 8; ++kk) {
        float4 w4 = *(const float4*)(c2_w + (long)(k0 + kk) * 1024 + n);
        #pragma unroll
        for (int b = 0; b < 8; ++b) {
            float s = ins[b][kk];
            acc[b].x = fmaf(s, w4.x, acc[b].x); acc[b].y = fmaf(s, w4.y, acc[b].y);
            acc[b].z = fmaf(s, w4.z, acc[b].z); acc[b].w = fmaf(s, w4.w, acc[b].w);
        }
    }
    #pragma unroll
    for (int b = 0; b < 8; ++b)
        *(float4*)(part + ((long)(ks * 8 + b)) * 1024 + n) = acc[b];
}

// ------- c3+c4 fused -------
__global__ __launch_bounds__(256) void c3m_k(const float* __restrict__ part2, const float* __restrict__ c2_b,
                                             const float* __restrict__ c3_w, const float* __restrict__ c3_b,
                                             const float* __restrict__ c4_w, const float* __restrict__ c4_b,
                                             float* __restrict__ out)
{
    __shared__ float Hs[1024];
    __shared__ float red[256];
    const int t = threadIdx.x, b = blockIdx.x;
    float4 acc4 = make_float4(0.f,0.f,0.f,0.f);
    #pragma unroll 4
    for (int ks = 0; ks < 128; ++ks) {
        float4 p = *(const float4*)(part2 + ((long)(ks * 8 + b)) * 1024 + t * 4);
        acc4.x += p.x; acc4.y += p.y; acc4.z += p.z; acc4.w += p.w;
    }
    {
        float4 bb = *(const float4*)(c2_b + t * 4);
        Hs[t*4+0] = fmaxf(acc4.x + bb.x, 0.f);
        Hs[t*4+1] = fmaxf(acc4.y + bb.y, 0.f);
        Hs[t*4+2] = fmaxf(acc4.z + bb.z, 0.f);
        Hs[t*4+3] = fmaxf(acc4.w + bb.w, 0.f);
    }
    __syncthreads();
    float a0 = 0.f, a1 = 0.f, a2 = 0.f, a3 = 0.f;
    #pragma unroll 8
    for (int k = 0; k < 1024; k += 4) {
        a0 = fmaf(Hs[k+0], c3_w[(long)(k+0)*256 + t], a0);
        a1 = fmaf(Hs[k+1], c3_w[(long)(k+1)*256 + t], a1);
        a2 = fmaf(Hs[k+2], c3_w[(long)(k+2)*256 + t], a2);
        a3 = fmaf(Hs[k+3], c3_w[(long)(k+3)*256 + t], a3);
    }
    float h3v = fmaxf((a0 + a1) + (a2 + a3) + c3_b[t], 0.f);
    red[t] = h3v * c4_w[t];
    __syncthreads();
    for (int off = 128; off > 0; off >>= 1) {
        if (t < off) red[t] += red[t + off];
        __syncthreads();
    }
    if (t == 0) out[b] = red[0] + c4_b[0];
}

extern "C" void kernel_launch(void* const* d_in, const int* in_sizes, int n_in,
                              void* d_out, int out_size, void* d_ws, size_t ws_size,
                              hipStream_t stream)
{
    const float* PE   = (const float*)d_in[0];
    const float* PFX  = (const float*)d_in[1];
    const float* CF   = (const float*)d_in[2];
    const float* emb_w = (const float*)d_in[3];  const float* emb_b = (const float*)d_in[4];
    const float* wq_w  = (const float*)d_in[5];  const float* wq_b  = (const float*)d_in[6];
    const float* wk_w  = (const float*)d_in[7];  const float* wk_b  = (const float*)d_in[8];
    const float* wv_w  = (const float*)d_in[9];  const float* wv_b  = (const float*)d_in[10];
    const float* wo_w  = (const float*)d_in[11]; const float* wo_b  = (const float*)d_in[12];
    const float* jp_w  = (const float*)d_in[13]; const float* jp_b  = (const float*)d_in[14];
    const float* jc_w  = (const float*)d_in[15]; const float* jc_b  = (const float*)d_in[16];
    const float* c1_w  = (const float*)d_in[17]; const float* c1_b  = (const float*)d_in[18];
    const float* c2_w  = (const float*)d_in[19]; const float* c2_b  = (const float*)d_in[20];
    const float* c3_w  = (const float*)d_in[21]; const float* c3_b  = (const float*)d_in[22];
    const float* c4_w  = (const float*)d_in[23]; const float* c4_b  = (const float*)d_in[24];

    float* ws     = (float*)d_ws;
    f16*  Qhi   = (f16*)ws;                        // 8*1024*128 fp16 = 524,288 float-slots
    f16*  Qlo   = (f16*)(ws + 524288);
    f16*  Khi   = (f16*)(ws + 1048576);
    f16*  Klo   = (f16*)(ws + 1572864);
    f16*  Vthi  = (f16*)(ws + 2097152);            // [8][128][1024] fp16
    f16*  Vtlo  = (f16*)(ws + 2621440);
    float* bufC   = ws + 3145728;                  //    65,536 (jc output)
    float* Opart  = bufC + 65536;                  // 4,096,000 (4-way flash partials)
    float* mpart  = Opart + 4096000;               //    32,000
    float* lpart  = mpart + 32000;                 //    32,000
    float* Asum   = lpart + 32000;                 //         8
    float* cpe    = Asum + 8;                      //     1,024
    float* bprime = cpe + 1024;                    //       128
    float* bufWvo = bprime + 128;                  //    16,384 (wv_w @ wo_w)
    float* bufbvo = bufWvo + 16384;                //       128
    float* part2  = ws;                            // c2 partials alias Q/K fp16 region
    float* PFbuf  = ws + 1048576;                  // [8][1000][128] protein_feats (alias K region post-flash)
    float* PJbuf  = ws + 2097152;                  // [8][1000][128] jp output (alias Vt region post-flash)
    // fp16 split weights (beyond main region)
    f16* WpThi = (f16*)(ws + 7430144);             // [128][320] f16 = 20,480 float slots
    f16* WpTlo = (f16*)(ws + 7450624);
    f16* WkThi = (f16*)(ws + 7471104);             // [128][128] f16 = 8,192 float slots
    f16* WkTlo = (f16*)(ws + 7479296);             // end = 7,487,488 floats (~30 MB)

    pre0_k<<<24, 256, 0, stream>>>(emb_w, emb_b, wq_w, wq_b, wk_w, wv_w, wv_b, wo_w, wo_b,
                                   WpThi, WpTlo, WkThi, WkTlo,
                                   bprime, bufWvo, bufbvo, Asum);
    qkv3_k<<<522, 256, 0, stream>>>(PE, PFX, WpThi, WpTlo, WkThi, WkTlo,
                                    bprime, wk_b, CF, jc_w, jc_b,
                                    Qhi, Qlo, Khi, Klo, Vthi, Vtlo, bufC);
    flash7_k<<<dim3(16, NSPLIT, 8), 256, 0, stream>>>(Qhi, Qlo, Khi, Klo, Vthi, Vtlo,
                                                      Opart, mpart, lpart);
    mt1ab_k<<<dim3(63, 8), 256, 0, stream>>>(Opart, mpart, lpart, bufWvo, bufbvo,
                                             jp_w, jp_b, PFbuf, PJbuf);
    mt2_k<<<dim3(63, 2, 8), 256, 0, stream>>>(PFbuf, PJbuf, bufC, CF, Asum, cpe);
    c12_k<<<128, 256, 0, stream>>>(cpe, Asum, c1_w, c1_b, c2_w, part2);
    c3m_k<<<8, 256, 0, stream>>>(part2, c2_b, c3_w, c3_b, c4_w, c4_b, (float*)d_out);
}